// Round 1
// baseline (559.541 us; speedup 1.0000x reference)
//
#include <hip/hip_runtime.h>

#define NW   8190      // n_win = L - WIN + 1
#define LSEQ 8192
#define HD   90
#define NB   64
#define AMPF 28.5f

// Accumulate hn[j] += s * Wrow[j] for j in [0,90). Wrow is 8B-aligned.
__device__ __forceinline__ void accum_row(float hn[HD], const float* __restrict__ Wrow, float s) {
  const float2* __restrict__ w2 = reinterpret_cast<const float2*>(Wrow);
#pragma unroll
  for (int jj = 0; jj < 45; ++jj) {
    float2 w = w2[jj];
    hn[2 * jj]     = fmaf(s, w.x, hn[2 * jj]);
    hn[2 * jj + 1] = fmaf(s, w.y, hn[2 * jj + 1]);
  }
}

__device__ __forceinline__ void load_bias(float hn[HD], const float* __restrict__ bias) {
  const float2* __restrict__ b2 = reinterpret_cast<const float2*>(bias);
#pragma unroll
  for (int jj = 0; jj < 45; ++jj) {
    float2 v = b2[jj];
    hn[2 * jj]     = v.x;
    hn[2 * jj + 1] = v.y;
  }
}

__global__ __launch_bounds__(128)
void dnpu_mlp_f32(const float* __restrict__ x, const float* __restrict__ cv,
                  const float* __restrict__ W1, const float* __restrict__ b1,
                  const float* __restrict__ W2, const float* __restrict__ b2,
                  const float* __restrict__ W3, const float* __restrict__ b3,
                  const float* __restrict__ W4, const float* __restrict__ b4,
                  const float* __restrict__ W5, const float* __restrict__ b5,
                  const float* __restrict__ W6, const float* __restrict__ b6,
                  float* __restrict__ out) {
  // per-thread private LDS slot for previous-layer activations (runtime-indexed reads)
  __shared__ float hbuf[128 * 91];   // stride 91 (odd) -> only 2-way bank aliasing (free)
  const int t = threadIdx.x;
  const int w = blockIdx.x * 128 + t;
  const int b = blockIdx.y;
  if (w >= NW) return;               // no __syncthreads anywhere; safe early-exit
  float* hl = &hbuf[t * 91];

  const float x0 = x[b * LSEQ + w];
  const float x1 = x[b * LSEQ + w + 1];
  const float x2 = x[b * LSEQ + w + 2];
  const float c0 = cv[0], c1 = cv[1], c2 = cv[2], c3 = cv[3];

  float hn[HD];

  // ---- layer 1: z = [c0, c1, x0, x1, x2, c2, c3], 7x90 ----
  load_bias(hn, b1);
  accum_row(hn, W1 + 0 * HD, c0);
  accum_row(hn, W1 + 1 * HD, c1);
  accum_row(hn, W1 + 2 * HD, x0);
  accum_row(hn, W1 + 3 * HD, x1);
  accum_row(hn, W1 + 4 * HD, x2);
  accum_row(hn, W1 + 5 * HD, c2);
  accum_row(hn, W1 + 6 * HD, c3);
#pragma unroll
  for (int j = 0; j < HD; ++j) hl[j] = fmaxf(hn[j], 0.0f);

  // ---- layers 2..5: 90x90 each ----
#pragma unroll 1
  for (int L = 0; L < 4; ++L) {
    const float* W    = (L == 0) ? W2 : (L == 1) ? W3 : (L == 2) ? W4 : W5;
    const float* bias = (L == 0) ? b2 : (L == 1) ? b3 : (L == 2) ? b4 : b5;
    load_bias(hn, bias);
#pragma unroll 1
    for (int i = 0; i < HD; ++i) {
      accum_row(hn, W + i * HD, hl[i]);   // hl[i]: 1 ds_read_b32 per 90 FMAs
    }
    if (L < 3) {
#pragma unroll
      for (int j = 0; j < HD; ++j) hl[j] = fmaxf(hn[j], 0.0f);
    }
  }

  // ---- layer 6: 90 -> 1, then * AMP ----
  float acc = b6[0];
#pragma unroll
  for (int j = 0; j < HD; ++j) acc = fmaf(fmaxf(hn[j], 0.0f), W6[j], acc);

  out[b * NW + w] = acc * AMPF;
}

extern "C" void kernel_launch(void* const* d_in, const int* in_sizes, int n_in,
                              void* d_out, int out_size, void* d_ws, size_t ws_size,
                              hipStream_t stream) {
  const float* x  = (const float*)d_in[0];
  const float* cv = (const float*)d_in[1];
  const float* W1 = (const float*)d_in[2];
  const float* b1 = (const float*)d_in[3];
  const float* W2 = (const float*)d_in[4];
  const float* b2 = (const float*)d_in[5];
  const float* W3 = (const float*)d_in[6];
  const float* b3 = (const float*)d_in[7];
  const float* W4 = (const float*)d_in[8];
  const float* b4 = (const float*)d_in[9];
  const float* W5 = (const float*)d_in[10];
  const float* b5 = (const float*)d_in[11];
  const float* W6 = (const float*)d_in[12];
  const float* b6 = (const float*)d_in[13];
  float* out = (float*)d_out;

  dim3 grid((NW + 127) / 128, NB);   // 64 x 64 blocks
  dim3 block(128);
  hipLaunchKernelGGL(dnpu_mlp_f32, grid, block, 0, stream,
                     x, cv, W1, b1, W2, b2, W3, b3, W4, b4, W5, b5, W6, b6, out);
}

// Round 2
// 87.398 us; speedup vs baseline: 6.4022x; 6.4022x over previous
//
#include <hip/hip_runtime.h>

#define NB   64
#define LSEQ 8192
#define NW   8190
#define HD   90
#define AMPF 28.5f
#define ASTRIDE 104   // padded activation row stride in halves (208 B, 16B-aligned)

typedef _Float16 half8 __attribute__((ext_vector_type(8)));
typedef float   f32x4 __attribute__((ext_vector_type(4)));

union FragU { uint4 u; half8 h; };

// ---------------- weight fragment pre-pack ----------------
// Fragment slot map (MUST match main kernel's A-fragment construction):
//   lane l: col = t*16 + (l&15), k = s*32 + (l>>4)*8 + i   (i = 0..7, halfword i)
// frag ids: 0..5   = layer1 (t=f, s=0, kin=7: rows 0..6 = W1, row 7 = b1)
//           6..77  = layers2..5 (fb=6+L*18, f=fb+t*3+s, kin=90, row 90 = bias)
//           78..80 = layer6 (t=0, s=f-78, nout=1, row 90 = b6)
__global__ void dnpu_pack(const float* __restrict__ W1, const float* __restrict__ b1,
                          const float* __restrict__ W2, const float* __restrict__ b2,
                          const float* __restrict__ W3, const float* __restrict__ b3,
                          const float* __restrict__ W4, const float* __restrict__ b4,
                          const float* __restrict__ W5, const float* __restrict__ b5,
                          const float* __restrict__ W6, const float* __restrict__ b6,
                          uint4* __restrict__ frags) {
  int tid = blockIdx.x * blockDim.x + threadIdx.x;
  if (tid >= 81 * 64) return;
  int f = tid >> 6, lane = tid & 63;
  int c = lane & 15, g = lane >> 4;
  const float* W; const float* bias; int t, s, kin, nout;
  if (f < 6) {
    W = W1; bias = b1; t = f; s = 0; kin = 7; nout = HD;
  } else if (f < 78) {
    int q = f - 6; int L = q / 18; int r = q % 18;
    t = r / 3; s = r % 3; kin = HD; nout = HD;
    W    = (L == 0) ? W2 : (L == 1) ? W3 : (L == 2) ? W4 : W5;
    bias = (L == 0) ? b2 : (L == 1) ? b3 : (L == 2) ? b4 : b5;
  } else {
    W = W6; bias = b6; t = 0; s = f - 78; kin = HD; nout = 1;
  }
  int col = t * 16 + c;
  FragU u;
#pragma unroll
  for (int i = 0; i < 8; ++i) {
    int k = s * 32 + g * 8 + i;
    float val = 0.f;
    if (col < nout) {
      if (k < kin)       val = W[k * nout + col];
      else if (k == kin) val = bias[col];
    }
    u.h[i] = (_Float16)val;
  }
  frags[f * 64 + lane] = u.u;
}

// ---------------- main MFMA MLP kernel ----------------
__global__ __launch_bounds__(256)
void dnpu_mfma(const float* __restrict__ x, const float* __restrict__ cv,
               const uint4* __restrict__ frags, float* __restrict__ out) {
  __shared__ __align__(16) _Float16 act[4][16][ASTRIDE];  // per-wave, no syncthreads
  const int tid  = threadIdx.x;
  const int lane = tid & 63, wid = tid >> 6;
  const int c = lane & 15, g = lane >> 4;
  const int b = blockIdx.y;
  const int rowbase = (blockIdx.x * 4 + wid) * 16;  // 16 windows per wave

  // ---- layer 1: z = [c0,c1,x0,x1,x2,c2,c3, 1(bias)] , K padded to 32 ----
  const float c0 = cv[0], c1 = cv[1], c2 = cv[2], c3 = cv[3];
  const float* xr = x + (size_t)b * LSEQ;
  const int w = rowbase + c;
  const float x0 = xr[min(w,     LSEQ - 1)];
  const float x1 = xr[min(w + 1, LSEQ - 1)];
  const float x2 = xr[min(w + 2, LSEQ - 1)];

  half8 A1;
  A1[0] = (_Float16)c0; A1[1] = (_Float16)c1;
  A1[2] = (_Float16)x0; A1[3] = (_Float16)x1; A1[4] = (_Float16)x2;
  A1[5] = (_Float16)c2; A1[6] = (_Float16)c3; A1[7] = (_Float16)1.0f;
  if (g != 0) {
#pragma unroll
    for (int i = 0; i < 8; ++i) A1[i] = (_Float16)0.f;
  }

  f32x4 acc[6];
  {
    FragU Bf[6];
#pragma unroll
    for (int t2 = 0; t2 < 6; ++t2) Bf[t2].u = frags[t2 * 64 + lane];
#pragma unroll
    for (int t2 = 0; t2 < 6; ++t2)
      acc[t2] = __builtin_amdgcn_mfma_f32_16x16x32_f16(A1, Bf[t2].h, (f32x4)(0.f), 0, 0, 0);
  }

  // ---- layers 2..5: 96x96 padded (bias in k=90 row, act col 90 = 1.0) ----
#pragma unroll 1
  for (int L = 0; L < 4; ++L) {
    // write relu(acc) -> act fp16; C layout: col = l&15 (+16*t), row = 4*(l>>4)+r
#pragma unroll
    for (int t2 = 0; t2 < 6; ++t2) {
      const int col = t2 * 16 + c;
#pragma unroll
      for (int r = 0; r < 4; ++r) {
        _Float16 hv = (_Float16)fmaxf(acc[t2][r], 0.f);
        if (col == HD) hv = (_Float16)1.0f;   // bias input column
        act[wid][g * 4 + r][col] = hv;
      }
    }
    asm volatile("s_waitcnt lgkmcnt(0)" ::: "memory");
    half8 A[3];
#pragma unroll
    for (int s = 0; s < 3; ++s)
      A[s] = *reinterpret_cast<const half8*>(&act[wid][c][s * 32 + g * 8]);

    const uint4* fb = frags + (size_t)(6 + L * 18) * 64 + lane;
    FragU Bf[18];
#pragma unroll
    for (int j = 0; j < 18; ++j) Bf[j].u = fb[(size_t)j * 64];
#pragma unroll
    for (int t2 = 0; t2 < 6; ++t2) {
      f32x4 a = (f32x4)(0.f);
#pragma unroll
      for (int s = 0; s < 3; ++s)
        a = __builtin_amdgcn_mfma_f32_16x16x32_f16(A[s], Bf[t2 * 3 + s].h, a, 0, 0, 0);
      acc[t2] = a;
    }
  }

  // ---- layer 6: 96 -> 16 (only col 0 real), bias via k=90 row ----
  {
#pragma unroll
    for (int t2 = 0; t2 < 6; ++t2) {
      const int col = t2 * 16 + c;
#pragma unroll
      for (int r = 0; r < 4; ++r) {
        _Float16 hv = (_Float16)fmaxf(acc[t2][r], 0.f);
        if (col == HD) hv = (_Float16)1.0f;
        act[wid][g * 4 + r][col] = hv;
      }
    }
    asm volatile("s_waitcnt lgkmcnt(0)" ::: "memory");
    half8 A[3];
#pragma unroll
    for (int s = 0; s < 3; ++s)
      A[s] = *reinterpret_cast<const half8*>(&act[wid][c][s * 32 + g * 8]);

    f32x4 o = (f32x4)(0.f);
#pragma unroll
    for (int s = 0; s < 3; ++s) {
      FragU Bf; Bf.u = frags[(size_t)(78 + s) * 64 + lane];
      o = __builtin_amdgcn_mfma_f32_16x16x32_f16(A[s], Bf.h, o, 0, 0, 0);
    }
    if (c == 0) {
#pragma unroll
      for (int r = 0; r < 4; ++r) {
        const int row = rowbase + g * 4 + r;
        if (row < NW) out[(size_t)b * NW + row] = (float)o[r] * AMPF;
      }
    }
  }
}

extern "C" void kernel_launch(void* const* d_in, const int* in_sizes, int n_in,
                              void* d_out, int out_size, void* d_ws, size_t ws_size,
                              hipStream_t stream) {
  const float* x  = (const float*)d_in[0];
  const float* cv = (const float*)d_in[1];
  const float* W1 = (const float*)d_in[2];
  const float* b1 = (const float*)d_in[3];
  const float* W2 = (const float*)d_in[4];
  const float* b2 = (const float*)d_in[5];
  const float* W3 = (const float*)d_in[6];
  const float* b3 = (const float*)d_in[7];
  const float* W4 = (const float*)d_in[8];
  const float* b4 = (const float*)d_in[9];
  const float* W5 = (const float*)d_in[10];
  const float* b5 = (const float*)d_in[11];
  const float* W6 = (const float*)d_in[12];
  const float* b6 = (const float*)d_in[13];
  float* out = (float*)d_out;
  uint4* frags = (uint4*)d_ws;   // 81 frags * 64 lanes * 16 B = 82,944 B

  hipLaunchKernelGGL(dnpu_pack, dim3(21), dim3(256), 0, stream,
                     W1, b1, W2, b2, W3, b3, W4, b4, W5, b5, W6, b6, frags);
  hipLaunchKernelGGL(dnpu_mfma, dim3(LSEQ / 64, NB), dim3(256), 0, stream,
                     x, cv, frags, out);
}

// Round 4
// 49.334 us; speedup vs baseline: 11.3418x; 1.7715x over previous
//
#include <hip/hip_runtime.h>

#define NB   64
#define LSEQ 8192
#define NW   8190
#define HD   90
#define AMPF 28.5f
#define NTILE 4

typedef _Float16 half8  __attribute__((ext_vector_type(8)));
typedef float    f32x16 __attribute__((ext_vector_type(16)));
typedef __fp16   fp16x2 __attribute__((ext_vector_type(2)));

union FragU { uint4 u; half8 h; };

__device__ __forceinline__ unsigned pk2(float a, float b) {
  fp16x2 v = __builtin_amdgcn_cvt_pkrtz(a, b);
  return __builtin_bit_cast(unsigned, v);
}

// ---------------- weight fragment pre-pack (A-operand, swapped formulation) ----
// D[n][w] = sum_k W[k][n] * H[k][w].  A-frag layout (mfma_f32_32x32x16_f16):
//   lane l: row n = 32*t2 + (l&31);  k = 16*ks + 8*(l>>5) + i   (i = 0..7)
// ids: 0..2   layer1  (t2 = f, ks = 0; kin=7, k==7 -> b1)
//      3..74  layers2-5 (f = 3 + L*18 + t2*6 + ks; kin=90, k==90 -> bias)
//      75..80 layer6  (ks = f-75; nout=1: only row n==0 nonzero)
__global__ void dnpu_pack(const float* __restrict__ W1, const float* __restrict__ b1,
                          const float* __restrict__ W2, const float* __restrict__ b2,
                          const float* __restrict__ W3, const float* __restrict__ b3,
                          const float* __restrict__ W4, const float* __restrict__ b4,
                          const float* __restrict__ W5, const float* __restrict__ b5,
                          const float* __restrict__ W6, const float* __restrict__ b6,
                          uint4* __restrict__ frags) {
  int tid = blockIdx.x * blockDim.x + threadIdx.x;
  if (tid >= 81 * 64) return;
  int f = tid >> 6, lane = tid & 63;
  int n = lane & 31, g = lane >> 5;
  const float* W; const float* bias; int t2, ks, kin, nout;
  if (f < 3) {
    W = W1; bias = b1; t2 = f; ks = 0; kin = 7; nout = HD;
  } else if (f < 75) {
    int q = f - 3; int L = q / 18; int r = q % 18;
    t2 = r / 6; ks = r % 6; kin = HD; nout = HD;
    W    = (L == 0) ? W2 : (L == 1) ? W3 : (L == 2) ? W4 : W5;
    bias = (L == 0) ? b2 : (L == 1) ? b3 : (L == 2) ? b4 : b5;
  } else {
    W = W6; bias = b6; t2 = 0; ks = f - 75; kin = HD; nout = 1;
  }
  int row = 32 * t2 + n;
  FragU u;
#pragma unroll
  for (int i = 0; i < 8; ++i) {
    int k = 16 * ks + 8 * g + i;
    float val = 0.f;
    if (row < nout) {
      if (k < kin)       val = W[k * nout + row];
      else if (k == kin) val = bias[row];
    }
    u.h[i] = (_Float16)val;
  }
  frags[f * 64 + lane] = u.u;
}

// ---- transition: acc (C-layout) -> next layer's B-frags, fully in-register ----
// C: lane l holds col w = l&31, row n = 32*t2 + (r&3) + 8*(r>>2) + 4*(l>>5).
// B-frag[ks=2u+par]: lane l needs col w = l&31 (same lane!), k' = n = 16ks+8g+i.
// Pack n-consecutive fp16 pairs, then one permlane32_swap per word pair:
//   after swap, lane-halves exchange so each lane holds its full i0..7 run.
__device__ __forceinline__ void transition(const f32x16 (&acc)[3], uint4 (&Bt)[6]) {
  unsigned P0[3][4], P1[3][4];
#pragma unroll
  for (int u = 0; u < 3; ++u) {
#pragma unroll
    for (int q = 0; q < 4; ++q) {
      P0[u][q] = pk2(fmaxf(acc[u][4 * q + 0], 0.f), fmaxf(acc[u][4 * q + 1], 0.f));
      P1[u][q] = pk2(fmaxf(acc[u][4 * q + 2], 0.f), fmaxf(acc[u][4 * q + 3], 0.f));
    }
  }
#pragma unroll
  for (int u = 0; u < 3; ++u) {
#pragma unroll
    for (int par = 0; par < 2; ++par) {
      unsigned w0 = P0[u][2 * par], w2 = P0[u][2 * par + 1];
      unsigned w1 = P1[u][2 * par], w3 = P1[u][2 * par + 1];
      asm("v_permlane32_swap_b32 %0, %1" : "+v"(w0), "+v"(w2));
      asm("v_permlane32_swap_b32 %0, %1" : "+v"(w1), "+v"(w3));
      Bt[2 * u + par] = make_uint4(w0, w1, w2, w3);
    }
  }
}

// ---------------- main kernel ----------------
__global__ __launch_bounds__(256, 2)
void dnpu_mfma(const float* __restrict__ x, const float* __restrict__ cv,
               const uint4* __restrict__ frags, float* __restrict__ out) {
  __shared__ uint4 lfr[72 * 64];             // layers 2-5 frags, 73,728 B
  const int tid  = threadIdx.x;
  const int lane = tid & 63, wid = tid >> 6;
  const int g = lane >> 5, c = lane & 31;
  const int b = blockIdx.y;

  // stage layers 2-5 weight frags to LDS once per block
  for (int i = tid; i < 72 * 64; i += 256) lfr[i] = frags[192 + i];
  __syncthreads();

  const float c0 = cv[0], c1 = cv[1], c2 = cv[2], c3 = cv[3];
  const float* xr = x + (size_t)b * LSEQ;
  const int rowbase0 = blockIdx.x * 512 + wid * 128;

  uint4 Bw[NTILE][6];   // per-tile activation B-frags (current layer's input)

  // ---- layer 1: K padded to 16; g=0 lanes hold [c0,c1,x0,x1,x2,c2,c3,1] ----
  {
    FragU Af[3];
#pragma unroll
    for (int t2 = 0; t2 < 3; ++t2) Af[t2].u = frags[t2 * 64 + lane];
#pragma unroll
    for (int t = 0; t < NTILE; ++t) {
      const int w  = rowbase0 + t * 32 + c;
      const int xi = (w < LSEQ - 3) ? w : (LSEQ - 3);
      const float x0 = xr[xi], x1 = xr[xi + 1], x2 = xr[xi + 2];
      half8 B1;
#pragma unroll
      for (int i = 0; i < 8; ++i) B1[i] = (_Float16)0.f;
      if (g == 0) {
        B1[0] = (_Float16)c0; B1[1] = (_Float16)c1;
        B1[2] = (_Float16)x0; B1[3] = (_Float16)x1; B1[4] = (_Float16)x2;
        B1[5] = (_Float16)c2; B1[6] = (_Float16)c3; B1[7] = (_Float16)1.0f;
      }
      f32x16 acc[3];
#pragma unroll
      for (int t2 = 0; t2 < 3; ++t2)
        acc[t2] = __builtin_amdgcn_mfma_f32_32x32x16_f16(Af[t2].h, B1, (f32x16)(0.f), 0, 0, 0);
      transition(acc, Bw[t]);
      Bw[t][5].y = g ? ((Bw[t][5].y & 0xFFFF0000u) | 0x3C00u) : Bw[t][5].y; // k=90 -> 1.0
    }
  }

  // ---- layers 2..5: frags from LDS once per layer, reused across NTILE tiles ----
#pragma unroll 1
  for (int L = 0; L < 4; ++L) {
    FragU Af[18];
#pragma unroll
    for (int j = 0; j < 18; ++j) Af[j].u = lfr[(L * 18 + j) * 64 + lane];
#pragma unroll
    for (int t = 0; t < NTILE; ++t) {
      f32x16 acc[3];
#pragma unroll
      for (int t2 = 0; t2 < 3; ++t2) {
        f32x16 a = (f32x16)(0.f);
#pragma unroll
        for (int ks = 0; ks < 6; ++ks)
          a = __builtin_amdgcn_mfma_f32_32x32x16_f16(
                Af[t2 * 6 + ks].h, __builtin_bit_cast(half8, Bw[t][ks]), a, 0, 0, 0);
        acc[t2] = a;
      }
      transition(acc, Bw[t]);
      Bw[t][5].y = g ? ((Bw[t][5].y & 0xFFFF0000u) | 0x3C00u) : Bw[t][5].y; // k=90 -> 1.0
    }
  }

  // ---- layer 6: 96 -> 1 (row 0 of one n-tile), then * AMP ----
  {
    FragU Af[6];
#pragma unroll
    for (int ks = 0; ks < 6; ++ks) Af[ks].u = frags[(75 + ks) * 64 + lane];
#pragma unroll
    for (int t = 0; t < NTILE; ++t) {
      f32x16 a = (f32x16)(0.f);
#pragma unroll
      for (int ks = 0; ks < 6; ++ks)
        a = __builtin_amdgcn_mfma_f32_32x32x16_f16(
              Af[ks].h, __builtin_bit_cast(half8, Bw[t][ks]), a, 0, 0, 0);
      if (g == 0) {
        const int row = rowbase0 + t * 32 + c;
        if (row < NW) out[(size_t)b * NW + row] = a[0] * AMPF;
      }
    }
  }
}

extern "C" void kernel_launch(void* const* d_in, const int* in_sizes, int n_in,
                              void* d_out, int out_size, void* d_ws, size_t ws_size,
                              hipStream_t stream) {
  const float* x  = (const float*)d_in[0];
  const float* cv = (const float*)d_in[1];
  const float* W1 = (const float*)d_in[2];
  const float* b1 = (const float*)d_in[3];
  const float* W2 = (const float*)d_in[4];
  const float* b2 = (const float*)d_in[5];
  const float* W3 = (const float*)d_in[6];
  const float* b3 = (const float*)d_in[7];
  const float* W4 = (const float*)d_in[8];
  const float* b4 = (const float*)d_in[9];
  const float* W5 = (const float*)d_in[10];
  const float* b5 = (const float*)d_in[11];
  const float* W6 = (const float*)d_in[12];
  const float* b6 = (const float*)d_in[13];
  float* out = (float*)d_out;
  uint4* frags = (uint4*)d_ws;   // 81 * 64 * 16 B = 82,944 B

  hipLaunchKernelGGL(dnpu_pack, dim3(21), dim3(256), 0, stream,
                     W1, b1, W2, b2, W3, b3, W4, b4, W5, b5, W6, b6, frags);
  hipLaunchKernelGGL(dnpu_mfma, dim3(16, NB), dim3(256), 0, stream,
                     x, cv, frags, out);
}